// Round 5
// baseline (362.443 us; speedup 1.0000x reference)
//
#include <hip/hip_runtime.h>

// ---------------------------------------------------------------------------
// Shapes (fixed): B=2, N=256, NODE_DIM=256, EDGE_DIM=64, H=8, D=32
// MFMA bf16 3-term split (AhBh + AhBl + AlBh, ~2^-17 rel err) for the two big
// edge GEMMs, fused with ne/logits/lrelu in MFMA C-layout.
// R3 (2nd resubmit; both prior rounds died at GPU acquisition, source never
// ran): edge kernel 512thr/8waves (16 waves/CU), K1 32x64 tiles + prep merged.
// ---------------------------------------------------------------------------

typedef unsigned short ushortT;
typedef short s16x8 __attribute__((ext_vector_type(8)));
typedef float f32x4 __attribute__((ext_vector_type(4)));

#define MFMA16(a, b, c) __builtin_amdgcn_mfma_f32_16x16x32_bf16(a, b, c, 0, 0, 0)

#define CF4(p) (*reinterpret_cast<const float4*>(p))
#define CF2(p) (*reinterpret_cast<const float2*>(p))
#define F4(p)  (*reinterpret_cast<float4*>(p))

__device__ __forceinline__ ushortT f2bf(float x) {
  union { float f; unsigned u; } v; v.f = x;
  unsigned r = (v.u + 0x7FFFu + ((v.u >> 16) & 1u)) >> 16;   // RNE
  return (ushortT)r;
}
__device__ __forceinline__ float bf2f(ushortT h) {
  union { unsigned u; float f; } v; v.u = ((unsigned)h) << 16;
  return v.f;
}

// --- generic 32x64-tile fp32 GEMM body (256 thr, 2x4 micro) ---------------
__device__ __forceinline__ void gemm32_body(
    const float* __restrict__ A, const float* __restrict__ B,
    const float* __restrict__ bias, float* __restrict__ C,
    int Nn, int K, int blk)
{
  __shared__ float As[16][36];   // [k][row]
  __shared__ float Bs[16][68];   // [k][col]
  const int t  = threadIdx.x;
  const int nbx = Nn >> 6;
  const int bx = blk % nbx;
  const int by = blk / nbx;
  const int r0 = by << 5, c0 = bx << 6;
  const int tx = t & 15, ty = t >> 4;    // ty 0..15 -> 2 rows each
  float acc[2][4];
#pragma unroll
  for (int i = 0; i < 2; ++i)
#pragma unroll
    for (int j = 0; j < 4; ++j) acc[i][j] = 0.f;

  for (int kt = 0; kt < K; kt += 16) {
    {
      const int r = t >> 3, k2 = (t & 7) << 1;
      const float2 a = CF2(A + (size_t)(r0 + r) * K + kt + k2);
      As[k2 + 0][r] = a.x; As[k2 + 1][r] = a.y;
    }
    {
      const int kk = t >> 4, c4 = (t & 15) << 2;
      F4(&Bs[kk][c4]) = CF4(B + (size_t)(kt + kk) * Nn + c0 + c4);
    }
    __syncthreads();
#pragma unroll
    for (int kk = 0; kk < 16; ++kk) {
      const float a0 = As[kk][ty * 2 + 0];
      const float a1 = As[kk][ty * 2 + 1];
      const float4 bv = F4(&Bs[kk][tx << 2]);
      const float bb[4] = {bv.x, bv.y, bv.z, bv.w};
#pragma unroll
      for (int cc = 0; cc < 4; ++cc) {
        acc[0][cc] = fmaf(a0, bb[cc], acc[0][cc]);
        acc[1][cc] = fmaf(a1, bb[cc], acc[1][cc]);
      }
    }
    __syncthreads();
  }
  const float4 bv = CF4(bias + c0 + (tx << 2));
  const float bb[4] = {bv.x, bv.y, bv.z, bv.w};
#pragma unroll
  for (int rr = 0; rr < 2; ++rr) {
    float4 o;
    o.x = acc[rr][0] + bb[0]; o.y = acc[rr][1] + bb[1];
    o.z = acc[rr][2] + bb[2]; o.w = acc[rr][3] + bb[3];
    F4(C + (size_t)(r0 + ty * 2 + rr) * Nn + c0 + (tx << 2)) = o;
  }
}

// --- K1 + weight-prep merged: blocks [0,192) do qkv GEMM, [192,256) prep ---
__global__ __launch_bounds__(256) void qkv_prep_kernel(
    const float* __restrict__ nodes, const float* __restrict__ W_qkv,
    const float* __restrict__ b_qkv, float* __restrict__ qkv,
    const float* __restrict__ W_ss, const float* __restrict__ W_edges,
    ushortT* __restrict__ WssT_h, ushortT* __restrict__ WssT_l,
    ushortT* __restrict__ WeT_h,  ushortT* __restrict__ WeT_l)
{
  if (blockIdx.x < 192) {
    gemm32_body(nodes, W_qkv, b_qkv, qkv, 768, 256, blockIdx.x);
    return;
  }
  const int idx = (blockIdx.x - 192) * 256 + threadIdx.x;   // 16384 threads
  for (int e = idx; e < 512 * 64; e += 16384) {
    const int c = e >> 6, i = e & 63;
    const float x = W_ss[i * 512 + c];
    const ushortT h = f2bf(x);
    WssT_h[e] = h;
    WssT_l[e] = f2bf(x - bf2f(h));
  }
  for (int e = idx; e < 64 * 256; e += 16384) {
    const int j = e >> 8, c = e & 255;
    const float x = W_edges[c * 64 + j];
    const ushortT h = f2bf(x);
    WeT_h[e] = h;
    WeT_l[e] = f2bf(x - bf2f(h));
  }
}

// --- K5 wrapper -------------------------------------------------------------
__global__ __launch_bounds__(256) void gemm32_kernel(
    const float* __restrict__ A, const float* __restrict__ B,
    const float* __restrict__ bias, float* __restrict__ C, int Nn, int K)
{
  gemm32_body(A, B, bias, C, Nn, K, blockIdx.x);
}

// --- K2: MFMA edge pipeline, 512 thr / 8 waves x 16 rows --------------------
// Block = (b, q, kh): 128 k-rows. Per chunk ch (64 output channels):
//   GEMM1 (ss shift+scale, K=64, 3-term) -> ne in C-layout -> logits (shfl)
//   -> lrelu -> bf16 split -> LDS (swizzled, wave-private rows) -> GEMM2.
__global__ __launch_bounds__(512, 4) void edge_mfma_kernel(
    const float* __restrict__ edges, const float* __restrict__ qkv,
    const ushortT* __restrict__ WssT_h, const ushortT* __restrict__ WssT_l,
    const float* __restrict__ b_ss,
    const ushortT* __restrict__ WeT_h, const ushortT* __restrict__ WeT_l,
    const float* __restrict__ b_edges,
    float* __restrict__ out_edges, float* __restrict__ logits)
{
  __shared__ ushortT Eh[128 * 64];
  __shared__ ushortT El[128 * 64];
  __shared__ ushortT Nh[128 * 64];
  __shared__ ushortT Nl[128 * 64];
  __shared__ float qv_l[256];

  const int t    = threadIdx.x;
  const int lane = t & 63;
  const int w    = t >> 6;          // wave 0..7
  const int l15  = lane & 15;
  const int lg   = lane >> 4;       // 0..3
  const int bid  = blockIdx.x;
  const int kh   = bid & 1;
  const int q    = (bid >> 1) & 255;
  const int b    = bid >> 9;
  const int k0   = kh << 7;         // 0 or 128
  const int rw   = w << 4;          // wave row base (16 rows/wave)

  if (t < 256) qv_l[t] = qkv[(size_t)(b * 256 + q) * 768 + t];

  // stage E tile: 128 rows x 64 ch, bf16 hi/lo, XOR-swizzled rows
  const float* eBase = edges + ((size_t)((b * 256 + q) * 256 + k0)) * 64;
#pragma unroll
  for (int u = 0; u < 4; ++u) {
    const int f = t + u * 512;            // float4 id 0..2047
    const int r = f >> 4, i4 = (f & 15) << 2;
    const float4 v = CF4(eBase + r * 64 + i4);
    const ushortT h0 = f2bf(v.x), h1 = f2bf(v.y), h2 = f2bf(v.z), h3 = f2bf(v.w);
    const ushortT e0 = f2bf(v.x - bf2f(h0)), e1 = f2bf(v.y - bf2f(h1)),
                  e2 = f2bf(v.z - bf2f(h2)), e3 = f2bf(v.w - bf2f(h3));
    int byte = r * 128 + i4 * 2; byte ^= (r & 7) << 4;
    *reinterpret_cast<ushort4*>(reinterpret_cast<char*>(Eh) + byte) = make_ushort4(h0, h1, h2, h3);
    *reinterpret_cast<ushort4*>(reinterpret_cast<char*>(El) + byte) = make_ushort4(e0, e1, e2, e3);
  }
  __syncthreads();

  const f32x4 zero4 = {0.f, 0.f, 0.f, 0.f};
  f32x4 accO[4];
#pragma unroll
  for (int jt = 0; jt < 4; ++jt) accO[jt] = zero4;

  for (int ch = 0; ch < 4; ++ch) {
    const int c0 = ch << 6;

    // GEMM1 accumulators, bias-initialized (bias depends on col only)
    f32x4 accS[4], accC[4];
#pragma unroll
    for (int ct = 0; ct < 4; ++ct) {
      const float bs = b_ss[c0 + ct * 16 + l15];
      const float bc = b_ss[256 + c0 + ct * 16 + l15];
      const f32x4 vs = {bs, bs, bs, bs}, vc = {bc, bc, bc, bc};
      accS[ct] = vs; accC[ct] = vc;
    }

    // ---- GEMM1: K=64 (2 k-steps of 32), 3-term split
#pragma unroll
    for (int ks = 0; ks < 2; ++ks) {
      const int row = rw + l15;
      int abyte = row * 128 + (32 * ks + 8 * lg) * 2; abyte ^= (row & 7) << 4;
      const s16x8 ah = *reinterpret_cast<const s16x8*>(reinterpret_cast<const char*>(Eh) + abyte);
      const s16x8 al = *reinterpret_cast<const s16x8*>(reinterpret_cast<const char*>(El) + abyte);
#pragma unroll
      for (int ct = 0; ct < 4; ++ct) {
        const size_t off = (size_t)(c0 + ct * 16 + l15) * 64 + 32 * ks + 8 * lg;
        const s16x8 bsh = *reinterpret_cast<const s16x8*>(WssT_h + off);
        const s16x8 bsl = *reinterpret_cast<const s16x8*>(WssT_l + off);
        const s16x8 bch = *reinterpret_cast<const s16x8*>(WssT_h + off + 16384);
        const s16x8 bcl = *reinterpret_cast<const s16x8*>(WssT_l + off + 16384);
        accS[ct] = MFMA16(ah, bsh, accS[ct]);
        accS[ct] = MFMA16(ah, bsl, accS[ct]);
        accS[ct] = MFMA16(al, bsh, accS[ct]);
        accC[ct] = MFMA16(ah, bch, accC[ct]);
        accC[ct] = MFMA16(ah, bcl, accC[ct]);
        accC[ct] = MFMA16(al, bch, accC[ct]);
      }
    }

    // ---- elementwise: ne = attn*(1+scale)+shift; logits partials; lrelu->LDS
    float lgacc[2][4];
#pragma unroll
    for (int hh = 0; hh < 2; ++hh)
#pragma unroll
      for (int r = 0; r < 4; ++r) lgacc[hh][r] = 0.f;

#pragma unroll
    for (int ct = 0; ct < 4; ++ct) {
      const float qvc = qv_l[c0 + ct * 16 + l15];
      const float* kvp = qkv + (size_t)(b * 256 + k0 + rw + lg * 4) * 768
                             + 256 + c0 + ct * 16 + l15;
#pragma unroll
      for (int r = 0; r < 4; ++r) {
        const float kvv = kvp[(size_t)r * 768];
        const float a  = qvc * kvv;
        const float ne = fmaf(a, accC[ct][r], a) + accS[ct][r];
        lgacc[ct >> 1][r] += ne;
        const float nel = ne > 0.f ? ne : 0.1f * ne;
        const ushortT nh = f2bf(nel);
        const ushortT nl = f2bf(nel - bf2f(nh));
        const int row = rw + lg * 4 + r;
        int byte = row * 128 + (ct * 16 + l15) * 2; byte ^= (row & 7) << 4;
        *reinterpret_cast<ushortT*>(reinterpret_cast<char*>(Nh) + byte) = nh;
        *reinterpret_cast<ushortT*>(reinterpret_cast<char*>(Nl) + byte) = nl;
      }
    }

    // logits: reduce over 16 lanes (cols) and write (heads 2ch, 2ch+1)
#pragma unroll
    for (int hh = 0; hh < 2; ++hh)
#pragma unroll
      for (int r = 0; r < 4; ++r) {
        float v = lgacc[hh][r];
        v += __shfl_xor(v, 1);
        v += __shfl_xor(v, 2);
        v += __shfl_xor(v, 4);
        v += __shfl_xor(v, 8);
        lgacc[hh][r] = v;
      }
    if (l15 == 0) {
#pragma unroll
      for (int hh = 0; hh < 2; ++hh) {
        float4 o;
        o.x = lgacc[hh][0] * 0.17677669529663687f;
        o.y = lgacc[hh][1] * 0.17677669529663687f;
        o.z = lgacc[hh][2] * 0.17677669529663687f;
        o.w = lgacc[hh][3] * 0.17677669529663687f;
        const int h = ch * 2 + hh;
        const int krow = k0 + rw + lg * 4;
        F4(logits + ((size_t)((b * 8 + h) * 256 + q)) * 256 + krow) = o;
      }
    }

    // ---- GEMM2 partial: K=64 of this chunk (wave-private LDS rows, no barrier)
#pragma unroll
    for (int ks = 0; ks < 2; ++ks) {
      const int row = rw + l15;
      int abyte = row * 128 + (32 * ks + 8 * lg) * 2; abyte ^= (row & 7) << 4;
      const s16x8 anh = *reinterpret_cast<const s16x8*>(reinterpret_cast<const char*>(Nh) + abyte);
      const s16x8 anl = *reinterpret_cast<const s16x8*>(reinterpret_cast<const char*>(Nl) + abyte);
#pragma unroll
      for (int jt = 0; jt < 4; ++jt) {
        const size_t off = (size_t)(jt * 16 + l15) * 256 + c0 + 32 * ks + 8 * lg;
        const s16x8 wh = *reinterpret_cast<const s16x8*>(WeT_h + off);
        const s16x8 wl = *reinterpret_cast<const s16x8*>(WeT_l + off);
        accO[jt] = MFMA16(anh, wh, accO[jt]);
        accO[jt] = MFMA16(anh, wl, accO[jt]);
        accO[jt] = MFMA16(anl, wh, accO[jt]);
      }
    }
  }

  // epilogue: out_edges[(b,q,k)][j] = accO + b_edges[j]
#pragma unroll
  for (int jt = 0; jt < 4; ++jt) {
    const float be = b_edges[jt * 16 + l15];
#pragma unroll
    for (int r = 0; r < 4; ++r) {
      const int krow = k0 + rw + lg * 4 + r;
      out_edges[((size_t)((b * 256 + q) * 256 + krow)) * 64 + jt * 16 + l15] =
          accO[jt][r] + be;
    }
  }
}

// --- K3: per-(b,h,k) softmax-over-q stats: m = max_q, r = 1/sum_q exp(x-m)
__global__ __launch_bounds__(256) void softmax_stats_kernel(
    const float* __restrict__ logits, float* __restrict__ mOut, float* __restrict__ rOut)
{
  __shared__ float sm[8][33], sx[8][33];
  const int bh = blockIdx.x >> 3, kc = blockIdx.x & 7;
  const int kl = threadIdx.x & 31, qg = threadIdx.x >> 5;
  const float* base = logits + (size_t)bh * 65536 + kc * 32 + kl;
  float arr[32];
#pragma unroll
  for (int i = 0; i < 32; ++i) arr[i] = base[(size_t)(qg * 32 + i) * 256];
  float m = arr[0];
#pragma unroll
  for (int i = 1; i < 32; ++i) m = fmaxf(m, arr[i]);
  float s = 0.f;
#pragma unroll
  for (int i = 0; i < 32; ++i) s += __expf(arr[i] - m);
  sm[qg][kl] = m; sx[qg][kl] = s;
  __syncthreads();
  if (threadIdx.x < 32) {
    float M = sm[0][kl];
#pragma unroll
    for (int g = 1; g < 8; ++g) M = fmaxf(M, sm[g][kl]);
    float S = 0.f;
#pragma unroll
    for (int g = 0; g < 8; ++g) S += sx[g][kl] * __expf(sm[g][kl] - M);
    mOut[bh * 256 + kc * 32 + kl] = M;
    rOut[bh * 256 + kc * 32 + kl] = 1.f / S;
  }
}

// --- K4: weighted[b,q,h*32+d] = sum_k exp(l-m_k)*r_k * v[k,h*32+d]  (fused P)
__global__ __launch_bounds__(256) void weighted_fused_kernel(
    const float* __restrict__ logits, const float* __restrict__ mOut,
    const float* __restrict__ rOut, const float* __restrict__ qkv,
    float* __restrict__ weighted)
{
  __shared__ float P[32][260];
  __shared__ float mc[256], rc[256];
  const int qt = blockIdx.x & 7, h = (blockIdx.x >> 3) & 7, b = blockIdx.x >> 6;
  const int bh = b * 8 + h;
  const int t = threadIdx.x;
  mc[t] = mOut[bh * 256 + t];
  rc[t] = rOut[bh * 256 + t];
  __syncthreads();
  const float* lb = logits + (size_t)bh * 65536 + (size_t)qt * 32 * 256;
#pragma unroll
  for (int u = 0; u < 8; ++u) {
    const int f = t + u * 256;          // float4 id 0..2047
    const int qq = f >> 6, k4 = (f & 63) << 2;
    const float4 v = CF4(lb + qq * 256 + k4);
    P[qq][k4 + 0] = __expf(v.x - mc[k4 + 0]) * rc[k4 + 0];
    P[qq][k4 + 1] = __expf(v.y - mc[k4 + 1]) * rc[k4 + 1];
    P[qq][k4 + 2] = __expf(v.z - mc[k4 + 2]) * rc[k4 + 2];
    P[qq][k4 + 3] = __expf(v.w - mc[k4 + 3]) * rc[k4 + 3];
  }
  __syncthreads();
  const int dg = t & 7, qq = t >> 3;
  const float* vb = qkv + (size_t)b * 196608 + 512 + h * 32 + dg * 4;
  float a0 = 0.f, a1 = 0.f, a2 = 0.f, a3 = 0.f;
#pragma unroll 4
  for (int k = 0; k < 256; ++k) {
    const float p = P[qq][k];
    const float4 v = CF4(vb + (size_t)k * 768);
    a0 = fmaf(p, v.x, a0); a1 = fmaf(p, v.y, a1);
    a2 = fmaf(p, v.z, a2); a3 = fmaf(p, v.w, a3);
  }
  float4 o; o.x = a0; o.y = a1; o.z = a2; o.w = a3;
  F4(weighted + ((size_t)(b * 256 + qt * 32 + qq)) * 256 + h * 32 + dg * 4) = o;
}

extern "C" void kernel_launch(void* const* d_in, const int* in_sizes, int n_in,
                              void* d_out, int out_size, void* d_ws, size_t ws_size,
                              hipStream_t stream) {
  const float* nodes   = (const float*)d_in[0];
  const float* edges   = (const float*)d_in[1];
  const float* W_qkv   = (const float*)d_in[2];
  const float* b_qkv   = (const float*)d_in[3];
  const float* W_ss    = (const float*)d_in[4];
  const float* b_ss    = (const float*)d_in[5];
  const float* W_nodes = (const float*)d_in[6];
  const float* b_nodes = (const float*)d_in[7];
  const float* W_edges = (const float*)d_in[8];
  const float* b_edges = (const float*)d_in[9];

  float* out_nodes = (float*)d_out;            // 131072 floats
  float* out_edges = out_nodes + 131072;       // 8388608 floats

  float* wsf      = (float*)d_ws;
  float* qkv      = wsf;                       // [2,256,768]
  float* logits   = wsf + 393216;              // [2,8,256,256]
  float* weighted = wsf + 1441792;             // [2,256,256]
  float* mcol     = wsf + 1572864;             // [16,256]
  float* rcol     = wsf + 1576960;             // [16,256]
  ushortT* wss    = (ushortT*)(wsf + 1581056); // bf16 region
  ushortT* WssT_h = wss;                       // 512*64
  ushortT* WssT_l = wss + 32768;
  ushortT* WeT_h  = wss + 65536;               // 64*256
  ushortT* WeT_l  = wss + 81920;               // end 98304 ushorts (~6.52 MB)

  // K1 (192 blocks) + weight prep (64 blocks) in one launch
  qkv_prep_kernel<<<256, 256, 0, stream>>>(nodes, W_qkv, b_qkv, qkv,
                                           W_ss, W_edges, WssT_h, WssT_l, WeT_h, WeT_l);
  // K2: fused edge pipeline
  edge_mfma_kernel<<<1024, 512, 0, stream>>>(edges, qkv, WssT_h, WssT_l, b_ss,
                                             WeT_h, WeT_l, b_edges, out_edges, logits);
  // K3: softmax-over-q stats
  softmax_stats_kernel<<<128, 256, 0, stream>>>(logits, mcol, rcol);
  // K4: weighted = P . V (P computed on the fly)
  weighted_fused_kernel<<<128, 256, 0, stream>>>(logits, mcol, rcol, qkv, weighted);
  // K5: new_nodes = weighted @ W_nodes + b_nodes
  gemm32_kernel<<<64, 256, 0, stream>>>(weighted, W_nodes, b_nodes, out_nodes, 256, 256);
}

// Round 6
// 227.689 us; speedup vs baseline: 1.5918x; 1.5918x over previous
//
#include <hip/hip_runtime.h>

// ---------------------------------------------------------------------------
// Shapes (fixed): B=2, N=256, NODE_DIM=256, EDGE_DIM=64, H=8, D=32
// MFMA bf16 3-term split (AhBh + AhBl + AlBh) for the two big edge GEMMs.
// R6: R2 geometry (4 waves x 32 rows, 256thr, launch_bounds(256,2)) +
//   - GEMM1 weight slice staged in LDS once per block per chunk (8x L2 cut)
//   - kv values prefetched to registers at chunk start
//   - epilogue bounced through LDS -> full-line coalesced float4 stores
//   - logits collected in LDS -> one coalesced float4 store per thread
//   - K4 split to 256 blocks
// ---------------------------------------------------------------------------

typedef unsigned short ushortT;
typedef short s16x8 __attribute__((ext_vector_type(8)));
typedef float f32x4 __attribute__((ext_vector_type(4)));

#define MFMA16(a, b, c) __builtin_amdgcn_mfma_f32_16x16x32_bf16(a, b, c, 0, 0, 0)

#define CF4(p) (*reinterpret_cast<const float4*>(p))
#define CF2(p) (*reinterpret_cast<const float2*>(p))
#define F4(p)  (*reinterpret_cast<float4*>(p))
#define F2(p)  (*reinterpret_cast<float2*>(p))

__device__ __forceinline__ ushortT f2bf(float x) {
  union { float f; unsigned u; } v; v.f = x;
  unsigned r = (v.u + 0x7FFFu + ((v.u >> 16) & 1u)) >> 16;   // RNE
  return (ushortT)r;
}
__device__ __forceinline__ float bf2f(ushortT h) {
  union { unsigned u; float f; } v; v.u = ((unsigned)h) << 16;
  return v.f;
}

// --- generic 32x64-tile fp32 GEMM body (256 thr, 2x4 micro) ---------------
__device__ __forceinline__ void gemm32_body(
    const float* __restrict__ A, const float* __restrict__ B,
    const float* __restrict__ bias, float* __restrict__ C,
    int Nn, int K, int blk)
{
  __shared__ float As[16][36];
  __shared__ float Bs[16][68];
  const int t  = threadIdx.x;
  const int nbx = Nn >> 6;
  const int bx = blk % nbx;
  const int by = blk / nbx;
  const int r0 = by << 5, c0 = bx << 6;
  const int tx = t & 15, ty = t >> 4;
  float acc[2][4];
#pragma unroll
  for (int i = 0; i < 2; ++i)
#pragma unroll
    for (int j = 0; j < 4; ++j) acc[i][j] = 0.f;

  for (int kt = 0; kt < K; kt += 16) {
    {
      const int r = t >> 3, k2 = (t & 7) << 1;
      const float2 a = CF2(A + (size_t)(r0 + r) * K + kt + k2);
      As[k2 + 0][r] = a.x; As[k2 + 1][r] = a.y;
    }
    {
      const int kk = t >> 4, c4 = (t & 15) << 2;
      F4(&Bs[kk][c4]) = CF4(B + (size_t)(kt + kk) * Nn + c0 + c4);
    }
    __syncthreads();
#pragma unroll
    for (int kk = 0; kk < 16; ++kk) {
      const float a0 = As[kk][ty * 2 + 0];
      const float a1 = As[kk][ty * 2 + 1];
      const float4 bv = F4(&Bs[kk][tx << 2]);
      const float bb[4] = {bv.x, bv.y, bv.z, bv.w};
#pragma unroll
      for (int cc = 0; cc < 4; ++cc) {
        acc[0][cc] = fmaf(a0, bb[cc], acc[0][cc]);
        acc[1][cc] = fmaf(a1, bb[cc], acc[1][cc]);
      }
    }
    __syncthreads();
  }
  const float4 bv = CF4(bias + c0 + (tx << 2));
  const float bb[4] = {bv.x, bv.y, bv.z, bv.w};
#pragma unroll
  for (int rr = 0; rr < 2; ++rr) {
    float4 o;
    o.x = acc[rr][0] + bb[0]; o.y = acc[rr][1] + bb[1];
    o.z = acc[rr][2] + bb[2]; o.w = acc[rr][3] + bb[3];
    F4(C + (size_t)(r0 + ty * 2 + rr) * Nn + c0 + (tx << 2)) = o;
  }
}

// --- K1 + weight-prep merged: blocks [0,192) qkv GEMM, [192,256) prep ------
__global__ __launch_bounds__(256) void qkv_prep_kernel(
    const float* __restrict__ nodes, const float* __restrict__ W_qkv,
    const float* __restrict__ b_qkv, float* __restrict__ qkv,
    const float* __restrict__ W_ss, const float* __restrict__ W_edges,
    ushortT* __restrict__ WssT_h, ushortT* __restrict__ WssT_l,
    ushortT* __restrict__ WeT_h,  ushortT* __restrict__ WeT_l)
{
  if (blockIdx.x < 192) {
    gemm32_body(nodes, W_qkv, b_qkv, qkv, 768, 256, blockIdx.x);
    return;
  }
  const int idx = (blockIdx.x - 192) * 256 + threadIdx.x;   // 16384 threads
  for (int e = idx; e < 512 * 64; e += 16384) {
    const int c = e >> 6, i = e & 63;
    const float x = W_ss[i * 512 + c];
    const ushortT h = f2bf(x);
    WssT_h[e] = h;
    WssT_l[e] = f2bf(x - bf2f(h));
  }
  for (int e = idx; e < 64 * 256; e += 16384) {
    const int j = e >> 8, c = e & 255;
    const float x = W_edges[c * 64 + j];
    const ushortT h = f2bf(x);
    WeT_h[e] = h;
    WeT_l[e] = f2bf(x - bf2f(h));
  }
}

// --- K5 wrapper -------------------------------------------------------------
__global__ __launch_bounds__(256) void gemm32_kernel(
    const float* __restrict__ A, const float* __restrict__ B,
    const float* __restrict__ bias, float* __restrict__ C, int Nn, int K)
{
  gemm32_body(A, B, bias, C, Nn, K, blockIdx.x);
}

// --- K2: MFMA edge pipeline -------------------------------------------------
// Block = (b, q, kh): 128 k-rows, 4 waves x 32 rows (rt=2). Per chunk ch:
//   stage W1 (GEMM1 weights, 32KB) into LDS (overlaying N area) -> barrier
//   kv prefetch to regs + GEMM1 (B frags from LDS) -> barrier
//   elementwise: ne, logits (shfl-reduce -> lgbuf), lrelu -> N (over W1)
//   GEMM2 (A = own-wave N rows, W2 direct from L2)
// Epilogue: accO -> LDS fp32 -> coalesced float4 out; lgbuf -> coalesced logits.
__global__ __launch_bounds__(256, 2) void edge_mfma_kernel(
    const float* __restrict__ edges, const float* __restrict__ qkv,
    const ushortT* __restrict__ WssT_h, const ushortT* __restrict__ WssT_l,
    const float* __restrict__ b_ss,
    const ushortT* __restrict__ WeT_h, const ushortT* __restrict__ WeT_l,
    const float* __restrict__ b_edges,
    float* __restrict__ out_edges, float* __restrict__ logits)
{
  __shared__ __align__(16) char pool[70656];
  // layout: [0,16K) Eh | [16K,32K) El | [32K,64K) N(hi,lo) / W1 overlay
  //         [64K,68K) lgbuf (1024 f) | [68K,69K) qv_l (256 f)
  ushortT* Eh = (ushortT*)pool;
  ushortT* El = (ushortT*)(pool + 16384);
  float* lgbuf = (float*)(pool + 65536);
  float* qv_l  = (float*)(pool + 69632 - 4096 + 4096); // = pool + 69632
  qv_l = (float*)(pool + 69632);

  const int t    = threadIdx.x;
  const int lane = t & 63;
  const int w    = t >> 6;          // wave 0..3
  const int l15  = lane & 15;
  const int lg   = lane >> 4;       // 0..3
  const int bid  = blockIdx.x;
  const int kh   = bid & 1;
  const int q    = (bid >> 1) & 255;
  const int b    = bid >> 9;
  const int k0   = kh << 7;
  const int rw   = w << 5;          // 32 rows per wave

  qv_l[t] = qkv[(size_t)(b * 256 + q) * 768 + t];

  // stage E tile: 128 rows x 64 ch, bf16 hi/lo, XOR-swizzled
  const float* eBase = edges + ((size_t)((b * 256 + q) * 256 + k0)) * 64;
#pragma unroll
  for (int u = 0; u < 8; ++u) {
    const int f = t + u * 256;            // float4 id 0..2047
    const int r = f >> 4, i4 = (f & 15) << 2;
    const float4 v = CF4(eBase + r * 64 + i4);
    const ushortT h0 = f2bf(v.x), h1 = f2bf(v.y), h2 = f2bf(v.z), h3 = f2bf(v.w);
    const ushortT e0 = f2bf(v.x - bf2f(h0)), e1 = f2bf(v.y - bf2f(h1)),
                  e2 = f2bf(v.z - bf2f(h2)), e3 = f2bf(v.w - bf2f(h3));
    int byte = r * 128 + i4 * 2; byte ^= (r & 7) << 4;
    *reinterpret_cast<ushort4*>((char*)Eh + byte) = make_ushort4(h0, h1, h2, h3);
    *reinterpret_cast<ushort4*>((char*)El + byte) = make_ushort4(e0, e1, e2, e3);
  }

  const f32x4 zero4 = {0.f, 0.f, 0.f, 0.f};
  f32x4 accO[2][4];
#pragma unroll
  for (int rt = 0; rt < 2; ++rt)
#pragma unroll
    for (int jt = 0; jt < 4; ++jt) accO[rt][jt] = zero4;

  for (int ch = 0; ch < 4; ++ch) {
    const int c0 = ch << 6;

    // ---- stage W1 (this chunk's GEMM1 weights) into N-area LDS, swizzled.
    // parts: 0=shift_hi 1=scale_hi 2=shift_lo 3=scale_lo ; [part][cc 64][k 64]
    __syncthreads();   // prev chunk's GEMM2 / E-stage done before overwrite
    {
      const ushortT* srcs[4] = {
        WssT_h + (size_t)c0 * 64, WssT_h + 16384 + (size_t)c0 * 64,
        WssT_l + (size_t)c0 * 64, WssT_l + 16384 + (size_t)c0 * 64 };
#pragma unroll
      for (int part = 0; part < 4; ++part) {
#pragma unroll
        for (int it = 0; it < 2; ++it) {
          const int id = t + it * 256;          // 0..511
          const int cc = id >> 3, k8 = (id & 7) << 3;
          int dbyte = 32768 + part * 8192 + cc * 128 + k8 * 2;
          dbyte ^= (cc & 7) << 4;
          *reinterpret_cast<s16x8*>(pool + dbyte) =
              *reinterpret_cast<const s16x8*>(srcs[part] + cc * 64 + k8);
        }
      }
    }
    __syncthreads();

    // ---- kv prefetch (independent of GEMM1 -> hides under MFMAs)
    float kvreg[2][4][4];
#pragma unroll
    for (int rt = 0; rt < 2; ++rt)
#pragma unroll
      for (int ct = 0; ct < 4; ++ct) {
        const float* kvp = qkv + (size_t)(b * 256 + k0 + rw + rt * 16 + lg * 4) * 768
                               + 256 + c0 + ct * 16 + l15;
#pragma unroll
        for (int r = 0; r < 4; ++r) kvreg[rt][ct][r] = kvp[(size_t)r * 768];
      }

    // ---- GEMM1: K=64 (2 k-steps of 32), 3-term, B from LDS
    f32x4 accS[2][4], accC[2][4];
#pragma unroll
    for (int ct = 0; ct < 4; ++ct) {
      const float bs = b_ss[c0 + ct * 16 + l15];
      const float bc = b_ss[256 + c0 + ct * 16 + l15];
      const f32x4 vs = {bs, bs, bs, bs}, vc = {bc, bc, bc, bc};
      accS[0][ct] = vs; accS[1][ct] = vs;
      accC[0][ct] = vc; accC[1][ct] = vc;
    }
#pragma unroll
    for (int ks = 0; ks < 2; ++ks) {
      s16x8 ah[2], al[2];
#pragma unroll
      for (int rt = 0; rt < 2; ++rt) {
        const int row = rw + rt * 16 + l15;
        int abyte = row * 128 + (32 * ks + 8 * lg) * 2; abyte ^= (row & 7) << 4;
        ah[rt] = *reinterpret_cast<const s16x8*>((const char*)Eh + abyte);
        al[rt] = *reinterpret_cast<const s16x8*>((const char*)El + abyte);
      }
#pragma unroll
      for (int ct = 0; ct < 4; ++ct) {
        const int cc = ct * 16 + l15;
        int wb = 32768 + cc * 128 + (32 * ks + 8 * lg) * 2; wb ^= (cc & 7) << 4;
        const s16x8 bsh = *reinterpret_cast<const s16x8*>(pool + wb);
        const s16x8 bch = *reinterpret_cast<const s16x8*>(pool + wb + 8192);
        const s16x8 bsl = *reinterpret_cast<const s16x8*>(pool + wb + 16384);
        const s16x8 bcl = *reinterpret_cast<const s16x8*>(pool + wb + 24576);
#pragma unroll
        for (int rt = 0; rt < 2; ++rt) {
          accS[rt][ct] = MFMA16(ah[rt], bsh, accS[rt][ct]);
          accS[rt][ct] = MFMA16(ah[rt], bsl, accS[rt][ct]);
          accS[rt][ct] = MFMA16(al[rt], bsh, accS[rt][ct]);
          accC[rt][ct] = MFMA16(ah[rt], bch, accC[rt][ct]);
          accC[rt][ct] = MFMA16(ah[rt], bcl, accC[rt][ct]);
          accC[rt][ct] = MFMA16(al[rt], bch, accC[rt][ct]);
        }
      }
    }
    __syncthreads();   // all waves done reading W1 before N overwrites it

    // ---- elementwise: ne, logits partials, lrelu -> N (hi/lo, swizzled)
    float lgacc[2][2][4];
#pragma unroll
    for (int rt = 0; rt < 2; ++rt)
#pragma unroll
      for (int hh = 0; hh < 2; ++hh)
#pragma unroll
        for (int r = 0; r < 4; ++r) lgacc[rt][hh][r] = 0.f;

#pragma unroll
    for (int rt = 0; rt < 2; ++rt) {
#pragma unroll
      for (int ct = 0; ct < 4; ++ct) {
        const float qvc = qv_l[c0 + ct * 16 + l15];
#pragma unroll
        for (int r = 0; r < 4; ++r) {
          const float a  = qvc * kvreg[rt][ct][r];
          const float ne = fmaf(a, accC[rt][ct][r], a) + accS[rt][ct][r];
          lgacc[rt][ct >> 1][r] += ne;
          const float nel = ne > 0.f ? ne : 0.1f * ne;
          const ushortT nh = f2bf(nel);
          const ushortT nl = f2bf(nel - bf2f(nh));
          const int row = rw + rt * 16 + lg * 4 + r;
          int byte = row * 128 + (ct * 16 + l15) * 2; byte ^= (row & 7) << 4;
          *reinterpret_cast<ushortT*>(pool + 32768 + byte) = nh;
          *reinterpret_cast<ushortT*>(pool + 49152 + byte) = nl;
        }
      }
    }

    // logits: reduce over 16 lanes -> lgbuf (heads 2ch, 2ch+1)
#pragma unroll
    for (int rt = 0; rt < 2; ++rt)
#pragma unroll
      for (int hh = 0; hh < 2; ++hh)
#pragma unroll
        for (int r = 0; r < 4; ++r) {
          float v = lgacc[rt][hh][r];
          v += __shfl_xor(v, 1);
          v += __shfl_xor(v, 2);
          v += __shfl_xor(v, 4);
          v += __shfl_xor(v, 8);
          lgacc[rt][hh][r] = v;
        }
    if (l15 == 0) {
#pragma unroll
      for (int rt = 0; rt < 2; ++rt)
#pragma unroll
        for (int hh = 0; hh < 2; ++hh)
#pragma unroll
          for (int r = 0; r < 4; ++r)
            lgbuf[(ch * 2 + hh) * 128 + rw + rt * 16 + lg * 4 + r] = lgacc[rt][hh][r];
    }

    // ---- GEMM2 partial (own-wave N rows; W2 direct from L2)
#pragma unroll
    for (int ks = 0; ks < 2; ++ks) {
      s16x8 anh[2], anl[2];
#pragma unroll
      for (int rt = 0; rt < 2; ++rt) {
        const int row = rw + rt * 16 + l15;
        int abyte = row * 128 + (32 * ks + 8 * lg) * 2; abyte ^= (row & 7) << 4;
        anh[rt] = *reinterpret_cast<const s16x8*>(pool + 32768 + abyte);
        anl[rt] = *reinterpret_cast<const s16x8*>(pool + 49152 + abyte);
      }
#pragma unroll
      for (int jt = 0; jt < 4; ++jt) {
        const size_t off = (size_t)(jt * 16 + l15) * 256 + c0 + 32 * ks + 8 * lg;
        const s16x8 wh = *reinterpret_cast<const s16x8*>(WeT_h + off);
        const s16x8 wl = *reinterpret_cast<const s16x8*>(WeT_l + off);
#pragma unroll
        for (int rt = 0; rt < 2; ++rt) {
          accO[rt][jt] = MFMA16(anh[rt], wh, accO[rt][jt]);
          accO[rt][jt] = MFMA16(anh[rt], wl, accO[rt][jt]);
          accO[rt][jt] = MFMA16(anl[rt], wh, accO[rt][jt]);
        }
      }
    }
  }

  // ---- epilogue: bounce accO through LDS (stride 68 floats), coalesced out
  __syncthreads();
  float* outb = (float*)pool;   // 128 x 68 floats = 34816 B (E+N dead)
#pragma unroll
  for (int rt = 0; rt < 2; ++rt)
#pragma unroll
    for (int jt = 0; jt < 4; ++jt) {
      const float be = b_edges[jt * 16 + l15];
#pragma unroll
      for (int r = 0; r < 4; ++r) {
        const int row = rw + rt * 16 + lg * 4 + r;
        outb[row * 68 + jt * 16 + l15] = accO[rt][jt][r] + be;
      }
    }
  __syncthreads();
  {
    float* oBase = out_edges + ((size_t)((b * 256 + q) * 256 + k0)) * 64;
#pragma unroll
    for (int u = 0; u < 8; ++u) {
      const int idx = t + u * 256;          // float4 id 0..2047
      const int row = idx >> 4, c4 = (idx & 15) << 2;
      float4 o;
      o.x = outb[row * 68 + c4 + 0]; o.y = outb[row * 68 + c4 + 1];
      o.z = outb[row * 68 + c4 + 2]; o.w = outb[row * 68 + c4 + 3];
      F4(oBase + (size_t)row * 64 + c4) = o;
    }
    // logits: thread t -> head t>>5, float4 (t&31)
    const int h = t >> 5, i4 = (t & 31) << 2;
    const float s = 0.17677669529663687f;
    float4 o;
    o.x = lgbuf[h * 128 + i4 + 0] * s; o.y = lgbuf[h * 128 + i4 + 1] * s;
    o.z = lgbuf[h * 128 + i4 + 2] * s; o.w = lgbuf[h * 128 + i4 + 3] * s;
    F4(logits + ((size_t)((b * 8 + h) * 256 + q)) * 256 + k0 + i4) = o;
  }
}

// --- K3: per-(b,h,k) softmax-over-q stats ----------------------------------
__global__ __launch_bounds__(256) void softmax_stats_kernel(
    const float* __restrict__ logits, float* __restrict__ mOut, float* __restrict__ rOut)
{
  __shared__ float sm[8][33], sx[8][33];
  const int bh = blockIdx.x >> 3, kc = blockIdx.x & 7;
  const int kl = threadIdx.x & 31, qg = threadIdx.x >> 5;
  const float* base = logits + (size_t)bh * 65536 + kc * 32 + kl;
  float arr[32];
#pragma unroll
  for (int i = 0; i < 32; ++i) arr[i] = base[(size_t)(qg * 32 + i) * 256];
  float m = arr[0];
#pragma unroll
  for (int i = 1; i < 32; ++i) m = fmaxf(m, arr[i]);
  float s = 0.f;
#pragma unroll
  for (int i = 0; i < 32; ++i) s += __expf(arr[i] - m);
  sm[qg][kl] = m; sx[qg][kl] = s;
  __syncthreads();
  if (threadIdx.x < 32) {
    float M = sm[0][kl];
#pragma unroll
    for (int g = 1; g < 8; ++g) M = fmaxf(M, sm[g][kl]);
    float S = 0.f;
#pragma unroll
    for (int g = 0; g < 8; ++g) S += sx[g][kl] * __expf(sm[g][kl] - M);
    mOut[bh * 256 + kc * 32 + kl] = M;
    rOut[bh * 256 + kc * 32 + kl] = 1.f / S;
  }
}

// --- K4: weighted = P.V, 256 blocks (16 q rows each), P on the fly ---------
__global__ __launch_bounds__(256) void weighted_fused_kernel(
    const float* __restrict__ logits, const float* __restrict__ mOut,
    const float* __restrict__ rOut, const float* __restrict__ qkv,
    float* __restrict__ weighted)
{
  __shared__ float P[16][260];
  __shared__ float mc[256], rc[256];
  const int qt = blockIdx.x & 15, h = (blockIdx.x >> 4) & 7, b = blockIdx.x >> 7;
  const int bh = b * 8 + h;
  const int t = threadIdx.x;
  mc[t] = mOut[bh * 256 + t];
  rc[t] = rOut[bh * 256 + t];
  __syncthreads();
  const float* lb = logits + (size_t)bh * 65536 + (size_t)qt * 16 * 256;
#pragma unroll
  for (int u = 0; u < 4; ++u) {
    const int f = t + u * 256;          // float4 id 0..1023
    const int qq = f >> 6, k4 = (f & 63) << 2;
    const float4 v = CF4(lb + qq * 256 + k4);
    P[qq][k4 + 0] = __expf(v.x - mc[k4 + 0]) * rc[k4 + 0];
    P[qq][k4 + 1] = __expf(v.y - mc[k4 + 1]) * rc[k4 + 1];
    P[qq][k4 + 2] = __expf(v.z - mc[k4 + 2]) * rc[k4 + 2];
    P[qq][k4 + 3] = __expf(v.w - mc[k4 + 3]) * rc[k4 + 3];
  }
  __syncthreads();
  const int dd = t & 15, qq = t >> 4;          // dd: 2 d each; qq: 0..15
  const float* vb = qkv + (size_t)b * 196608 + 512 + h * 32 + dd * 2;
  float a0 = 0.f, a1 = 0.f;
#pragma unroll 8
  for (int k = 0; k < 256; ++k) {
    const float p = P[qq][k];
    const float2 v = CF2(vb + (size_t)k * 768);
    a0 = fmaf(p, v.x, a0); a1 = fmaf(p, v.y, a1);
  }
  float2 o; o.x = a0; o.y = a1;
  F2(weighted + ((size_t)(b * 256 + qt * 16 + qq)) * 256 + h * 32 + dd * 2) = o;
}

extern "C" void kernel_launch(void* const* d_in, const int* in_sizes, int n_in,
                              void* d_out, int out_size, void* d_ws, size_t ws_size,
                              hipStream_t stream) {
  const float* nodes   = (const float*)d_in[0];
  const float* edges   = (const float*)d_in[1];
  const float* W_qkv   = (const float*)d_in[2];
  const float* b_qkv   = (const float*)d_in[3];
  const float* W_ss    = (const float*)d_in[4];
  const float* b_ss    = (const float*)d_in[5];
  const float* W_nodes = (const float*)d_in[6];
  const float* b_nodes = (const float*)d_in[7];
  const float* W_edges = (const float*)d_in[8];
  const float* b_edges = (const float*)d_in[9];

  float* out_nodes = (float*)d_out;            // 131072 floats
  float* out_edges = out_nodes + 131072;       // 8388608 floats

  float* wsf      = (float*)d_ws;
  float* qkv      = wsf;                       // [2,256,768]
  float* logits   = wsf + 393216;              // [2,8,256,256]
  float* weighted = wsf + 1441792;             // [2,256,256]
  float* mcol     = wsf + 1572864;             // [16,256]
  float* rcol     = wsf + 1576960;             // [16,256]
  ushortT* wss    = (ushortT*)(wsf + 1581056); // bf16 region
  ushortT* WssT_h = wss;                       // 512*64
  ushortT* WssT_l = wss + 32768;
  ushortT* WeT_h  = wss + 65536;               // 64*256
  ushortT* WeT_l  = wss + 81920;               // end 98304 ushorts (~6.52 MB)

  qkv_prep_kernel<<<256, 256, 0, stream>>>(nodes, W_qkv, b_qkv, qkv,
                                           W_ss, W_edges, WssT_h, WssT_l, WeT_h, WeT_l);
  edge_mfma_kernel<<<1024, 256, 0, stream>>>(edges, qkv, WssT_h, WssT_l, b_ss,
                                             WeT_h, WeT_l, b_edges, out_edges, logits);
  softmax_stats_kernel<<<128, 256, 0, stream>>>(logits, mcol, rcol);
  weighted_fused_kernel<<<256, 256, 0, stream>>>(logits, mcol, rcol, qkv, weighted);
  gemm32_kernel<<<64, 256, 0, stream>>>(weighted, W_nodes, b_nodes, out_nodes, 256, 256);
}